// Round 5
// baseline (556.535 us; speedup 1.0000x reference)
//
#include <hip/hip_runtime.h>
#include <hip/hip_bf16.h>

#define N_NODES 50000
#define F_IN    602
#define H_DIM   32
#define C_OUT   41
#define E_EDGES 800000
#define BN_EPS  1e-5f

typedef short bf16x8 __attribute__((ext_vector_type(8)));
typedef float f32x4  __attribute__((ext_vector_type(4)));

__device__ inline unsigned short f2bf(float f) {
  unsigned int u = __builtin_bit_cast(unsigned int, f);
  unsigned int r = (u + 0x7FFFu + ((u >> 16) & 1u)) >> 16;
  return (unsigned short)r;
}

// ---------------------------------------------------------------------------
// K1: p = x @ W1a via split-bf16 MFMA (xh*wh + xl*wh + xh*wl).
// 64-row tile, 4 waves, wave = 16 rows x 32 cols. BK=32, 19 chunks,
// register prefetch, 2 barriers/chunk. (unchanged from round 4 — correct,
// <68 us)
// ---------------------------------------------------------------------------
__global__ __launch_bounds__(256) void k_gemm_mfma(
    const float* __restrict__ x, const float* __restrict__ W,
    float* __restrict__ p) {
  __shared__ unsigned short xh[64 * 40], xl[64 * 40];
  __shared__ unsigned short wh[32 * 40], wl[32 * 40];
  const int tid = threadIdx.x;
  const int wv = tid >> 6, ln = tid & 63;
  const int m = ln & 15, q = ln >> 4;
  const int r0 = blockIdx.x * 64;

  const int srow = tid >> 4, ks2 = tid & 15;
  const int wk = tid >> 3, c4 = tid & 7;

  float2 xr[4];
  float4 wr;

  auto prefetch = [&](int k0) {
    #pragma unroll
    for (int pp = 0; pp < 4; pp++) {
      int rr = r0 + srow + 16 * pp;
      int k = k0 + 2 * ks2;
      float2 v = {0.f, 0.f};
      if (rr < N_NODES && k <= F_IN - 2) v = *(const float2*)(x + (size_t)rr * F_IN + k);
      xr[pp] = v;
    }
    {
      int k = k0 + wk;
      float4 v = {0.f, 0.f, 0.f, 0.f};
      if (k < F_IN) v = *(const float4*)(W + (size_t)k * H_DIM + 4 * c4);
      wr = v;
    }
  };

  f32x4 acc0 = {0.f, 0.f, 0.f, 0.f};
  f32x4 acc1 = {0.f, 0.f, 0.f, 0.f};

  prefetch(0);

  unsigned int* xh32 = (unsigned int*)xh;
  unsigned int* xl32 = (unsigned int*)xl;

  for (int ch = 0; ch < 19; ch++) {
    __syncthreads();
    #pragma unroll
    for (int pp = 0; pp < 4; pp++) {
      int row = srow + 16 * pp;
      float2 v = xr[pp];
      unsigned short h0 = f2bf(v.x), h1 = f2bf(v.y);
      float f0 = __builtin_bit_cast(float, (unsigned int)h0 << 16);
      float f1 = __builtin_bit_cast(float, (unsigned int)h1 << 16);
      unsigned short l0 = f2bf(v.x - f0), l1 = f2bf(v.y - f1);
      xh32[row * 20 + ks2] = (unsigned int)h0 | ((unsigned int)h1 << 16);
      xl32[row * 20 + ks2] = (unsigned int)l0 | ((unsigned int)l1 << 16);
    }
    {
      float wf[4] = {wr.x, wr.y, wr.z, wr.w};
      #pragma unroll
      for (int i = 0; i < 4; i++) {
        unsigned short hh = f2bf(wf[i]);
        float fh = __builtin_bit_cast(float, (unsigned int)hh << 16);
        unsigned short ll = f2bf(wf[i] - fh);
        wh[(4 * c4 + i) * 40 + wk] = hh;
        wl[(4 * c4 + i) * 40 + wk] = ll;
      }
    }
    __syncthreads();
    if (ch < 18) prefetch((ch + 1) * 32);

    const int abase = (16 * wv + m) * 40 + q * 8;
    const int bbase = m * 40 + q * 8;
    bf16x8 axh = *(const bf16x8*)&xh[abase];
    bf16x8 axl = *(const bf16x8*)&xl[abase];
    bf16x8 b0h = *(const bf16x8*)&wh[bbase];
    bf16x8 b0l = *(const bf16x8*)&wl[bbase];
    bf16x8 b1h = *(const bf16x8*)&wh[bbase + 16 * 40];
    bf16x8 b1l = *(const bf16x8*)&wl[bbase + 16 * 40];
    acc0 = __builtin_amdgcn_mfma_f32_16x16x32_bf16(axh, b0h, acc0, 0, 0, 0);
    acc1 = __builtin_amdgcn_mfma_f32_16x16x32_bf16(axh, b1h, acc1, 0, 0, 0);
    acc0 = __builtin_amdgcn_mfma_f32_16x16x32_bf16(axl, b0h, acc0, 0, 0, 0);
    acc1 = __builtin_amdgcn_mfma_f32_16x16x32_bf16(axl, b1h, acc1, 0, 0, 0);
    acc0 = __builtin_amdgcn_mfma_f32_16x16x32_bf16(axh, b0l, acc0, 0, 0, 0);
    acc1 = __builtin_amdgcn_mfma_f32_16x16x32_bf16(axh, b1l, acc1, 0, 0, 0);
  }

  #pragma unroll
  for (int reg = 0; reg < 4; reg++) {
    int rowg = r0 + 16 * wv + q * 4 + reg;
    if (rowg < N_NODES) {
      p[(size_t)rowg * H_DIM + m]      = acc0[reg];
      p[(size_t)rowg * H_DIM + m + 16] = acc1[reg];
    }
  }
}

// ---------------------------------------------------------------------------
// CSR build
// ---------------------------------------------------------------------------
__global__ __launch_bounds__(256) void k_hist(const int* __restrict__ row,
                                              int* __restrict__ deg) {
  int e = blockIdx.x * 256 + threadIdx.x;
  if (e < E_EDGES) atomicAdd(&deg[row[e]], 1);
}

// Single-block scan over 50000 degrees -> start[], cursor[] (exclusive prefix)
#define SCAN_T 1024
#define SCAN_PER 49   // 1024*49 = 50176 >= 50000
__global__ __launch_bounds__(SCAN_T) void k_scan1(
    const int* __restrict__ deg, int* __restrict__ start,
    int* __restrict__ cursor) {
  __shared__ int sc[SCAN_T];
  const int t = threadIdx.x;
  const int base = t * SCAN_PER;
  int lsum = 0;
  #pragma unroll 7
  for (int j = 0; j < SCAN_PER; j++) {
    int idx = base + j;
    if (idx < N_NODES) lsum += deg[idx];
  }
  sc[t] = lsum;
  __syncthreads();
  #pragma unroll
  for (int off = 1; off < SCAN_T; off <<= 1) {
    int u = (t >= off) ? sc[t - off] : 0;
    __syncthreads();
    sc[t] += u;
    __syncthreads();
  }
  int run = sc[t] - lsum;   // exclusive prefix for this thread's segment
  #pragma unroll 7
  for (int j = 0; j < SCAN_PER; j++) {
    int idx = base + j;
    if (idx < N_NODES) {
      start[idx] = run;
      cursor[idx] = run;
      run += deg[idx];
    }
  }
  if (t == 0) start[N_NODES] = E_EDGES;
}

__global__ __launch_bounds__(256) void k_fill(const int* __restrict__ row,
                                              const int* __restrict__ col,
                                              int* __restrict__ cursor,
                                              int* __restrict__ ecol) {
  int e = blockIdx.x * 256 + threadIdx.x;
  if (e < E_EDGES) {
    int pos = atomicAdd(&cursor[row[e]], 1);
    ecol[pos] = col[e];
  }
}

// ---------------------------------------------------------------------------
// Gather-aggregate: z[n][c] = p[n][c] + b[c] + sum_{e in CSR[n]} p[ecol[e]][c]
// One half-wave per node (6250 blocks), unroll 8: 8 independent p-loads in
// flight per chain step -> latency-hiding via MLP + TLP.
// ---------------------------------------------------------------------------
__global__ __launch_bounds__(256) void k_gather(
    const float* __restrict__ p, const float* __restrict__ b,
    const int* __restrict__ start, const int* __restrict__ ecol,
    float* __restrict__ z) {
  int hw = (blockIdx.x * 256 + threadIdx.x) >> 5;
  int c = threadIdx.x & 31;
  if (hw >= N_NODES) return;
  int s = start[hw], e = start[hw + 1];
  float acc = p[(size_t)hw * H_DIM + c] + b[c];
  int i = s;
  for (; i + 7 < e; i += 8) {
    int s0 = ecol[i],     s1 = ecol[i + 1], s2 = ecol[i + 2], s3 = ecol[i + 3];
    int s4 = ecol[i + 4], s5 = ecol[i + 5], s6 = ecol[i + 6], s7 = ecol[i + 7];
    float v0 = p[(size_t)s0 * H_DIM + c];
    float v1 = p[(size_t)s1 * H_DIM + c];
    float v2 = p[(size_t)s2 * H_DIM + c];
    float v3 = p[(size_t)s3 * H_DIM + c];
    float v4 = p[(size_t)s4 * H_DIM + c];
    float v5 = p[(size_t)s5 * H_DIM + c];
    float v6 = p[(size_t)s6 * H_DIM + c];
    float v7 = p[(size_t)s7 * H_DIM + c];
    acc += v0; acc += v1; acc += v2; acc += v3;
    acc += v4; acc += v5; acc += v6; acc += v7;
  }
  for (; i + 3 < e; i += 4) {
    int s0 = ecol[i], s1 = ecol[i + 1], s2 = ecol[i + 2], s3 = ecol[i + 3];
    float v0 = p[(size_t)s0 * H_DIM + c];
    float v1 = p[(size_t)s1 * H_DIM + c];
    float v2 = p[(size_t)s2 * H_DIM + c];
    float v3 = p[(size_t)s3 * H_DIM + c];
    acc += v0; acc += v1; acc += v2; acc += v3;
  }
  for (; i < e; i++) acc += p[(size_t)ecol[i] * H_DIM + c];
  z[(size_t)hw * H_DIM + c] = acc;
}

// ---------------------------------------------------------------------------
// Fallback path (ws too small for CSR)
// ---------------------------------------------------------------------------
__global__ __launch_bounds__(256) void k_zinit(const float* __restrict__ p,
                                               const float* __restrict__ b,
                                               float* __restrict__ z) {
  int i = blockIdx.x * 256 + threadIdx.x;
  if (i < N_NODES * H_DIM) z[i] = p[i] + b[i & 31];
}

__global__ __launch_bounds__(256) void k_scatter(
    const int* __restrict__ row, const int* __restrict__ col,
    const float* __restrict__ p, float* __restrict__ z) {
  long long t = (long long)blockIdx.x * 256 + threadIdx.x;
  int e = (int)(t >> 5);
  int c = (int)(t & 31);
  if (e < E_EDGES) {
    int s = col[e], d = row[e];
    atomicAdd(&z[(size_t)d * H_DIM + c], p[(size_t)s * H_DIM + c]);
  }
}

// ---------------------------------------------------------------------------
// K3: hpre = relu(z) @ W + b  (N x 32 x 32), fused BN partial sums
// ---------------------------------------------------------------------------
__global__ __launch_bounds__(256) void k_mlp_stats(
    const float* __restrict__ z, const float* __restrict__ W,
    const float* __restrict__ b, float* __restrict__ hpre,
    float* __restrict__ stats) {
  __shared__ float as_[64 * 36];
  __shared__ float ws[32 * 36];
  __shared__ float red[512];
  const int tid = threadIdx.x;
  for (int i = tid; i < 1024; i += 256) {
    int k = i >> 5, c = i & 31;
    ws[c * 36 + k] = W[(size_t)k * H_DIM + c];
  }
  const int r0 = blockIdx.x * 64;
  for (int i = tid; i < 2048; i += 256) {
    int r = i >> 5, c = i & 31;
    int gr = r0 + r;
    float v = (gr < N_NODES) ? z[(size_t)gr * H_DIM + c] : 0.f;
    as_[r * 36 + c] = fmaxf(v, 0.f);
  }
  __syncthreads();
  const int c = tid & 31, rg = tid >> 5;
  float4 wc[8];
  #pragma unroll
  for (int q = 0; q < 8; q++) wc[q] = *(float4*)&ws[c * 36 + q * 4];
  const float bc = b[c];
  float lsum = 0.f, lsq = 0.f;
  #pragma unroll
  for (int i = 0; i < 8; i++) {
    int r = rg * 8 + i;
    float a = bc;
    #pragma unroll
    for (int q = 0; q < 8; q++) {
      float4 h4 = *(float4*)&as_[r * 36 + q * 4];
      a += h4.x * wc[q].x + h4.y * wc[q].y + h4.z * wc[q].z + h4.w * wc[q].w;
    }
    int gr = r0 + r;
    if (gr < N_NODES) {
      hpre[(size_t)gr * H_DIM + c] = a;
      lsum += a; lsq += a * a;
    }
  }
  __syncthreads();
  red[tid] = lsum; red[256 + tid] = lsq;
  __syncthreads();
  if (tid < 32) {
    float s = 0.f, q = 0.f;
    #pragma unroll
    for (int g = 0; g < 8; g++) { s += red[g * 32 + tid]; q += red[256 + g * 32 + tid]; }
    atomicAdd(&stats[tid], s);
    atomicAdd(&stats[32 + tid], q);
  }
}

// ---------------------------------------------------------------------------
// K5: p = BN(hpre) @ W  (BN finalize folded in from raw stats)
// ---------------------------------------------------------------------------
__global__ __launch_bounds__(256) void k_gemm32_affine(
    const float* __restrict__ hpre, const float* __restrict__ stats,
    const float* __restrict__ g, const float* __restrict__ be,
    const float* __restrict__ W, float* __restrict__ p) {
  __shared__ float hs[64 * 36];
  __shared__ float ws[32 * 36];
  __shared__ float ssl[64];
  const int tid = threadIdx.x;
  if (tid < 32) {
    float m = stats[tid] * (1.f / N_NODES);
    float v = stats[32 + tid] * (1.f / N_NODES) - m * m;
    float sc = g[tid] * rsqrtf(v + BN_EPS);
    ssl[tid] = sc;
    ssl[32 + tid] = be[tid] - m * sc;
  }
  for (int i = tid; i < 1024; i += 256) {
    int k = i >> 5, c = i & 31;
    ws[c * 36 + k] = W[(size_t)k * H_DIM + c];
  }
  __syncthreads();
  const int r0 = blockIdx.x * 64;
  for (int i = tid; i < 2048; i += 256) {
    int r = i >> 5, c = i & 31;
    int gr = r0 + r;
    float v = (gr < N_NODES) ? hpre[(size_t)gr * H_DIM + c] * ssl[c] + ssl[32 + c] : 0.f;
    hs[r * 36 + c] = v;
  }
  __syncthreads();
  const int c = tid & 31, rg = tid >> 5;
  float4 wc[8];
  #pragma unroll
  for (int q = 0; q < 8; q++) wc[q] = *(float4*)&ws[c * 36 + q * 4];
  #pragma unroll
  for (int i = 0; i < 8; i++) {
    int r = rg * 8 + i;
    float a = 0.f;
    #pragma unroll
    for (int q = 0; q < 8; q++) {
      float4 h4 = *(float4*)&hs[r * 36 + q * 4];
      a += h4.x * wc[q].x + h4.y * wc[q].y + h4.z * wc[q].z + h4.w * wc[q].w;
    }
    int gr = r0 + r;
    if (gr < N_NODES) p[(size_t)gr * H_DIM + c] = a;
  }
}

// ---------------------------------------------------------------------------
// K6: heads: out = relu(BN(hpre)@Wf1 + bf1) @ Wf2 + bf2 (BN folded in)
// ---------------------------------------------------------------------------
__global__ __launch_bounds__(256) void k_heads(
    const float* __restrict__ hpre, const float* __restrict__ stats,
    const float* __restrict__ g, const float* __restrict__ be,
    const float* __restrict__ W1, const float* __restrict__ b1,
    const float* __restrict__ W2, const float* __restrict__ b2,
    float* __restrict__ out) {
  __shared__ float hs[64 * 36];
  __shared__ float fs[64 * 36];
  __shared__ float w1[32 * 36];
  __shared__ float w2[41 * 36];
  __shared__ float ssl[64];
  const int tid = threadIdx.x;
  if (tid < 32) {
    float m = stats[tid] * (1.f / N_NODES);
    float v = stats[32 + tid] * (1.f / N_NODES) - m * m;
    float sc = g[tid] * rsqrtf(v + BN_EPS);
    ssl[tid] = sc;
    ssl[32 + tid] = be[tid] - m * sc;
  }
  for (int i = tid; i < 1024; i += 256) {
    int k = i >> 5, c = i & 31;
    w1[c * 36 + k] = W1[(size_t)k * H_DIM + c];
  }
  for (int i = tid; i < 41 * 32; i += 256) {
    int j = i >> 5, k = i & 31;
    w2[j * 36 + k] = W2[(size_t)k * C_OUT + j];
  }
  __syncthreads();
  const int r0 = blockIdx.x * 64;
  for (int i = tid; i < 2048; i += 256) {
    int r = i >> 5, c = i & 31;
    int gr = r0 + r;
    hs[r * 36 + c] = (gr < N_NODES) ? hpre[(size_t)gr * H_DIM + c] * ssl[c] + ssl[32 + c] : 0.f;
  }
  __syncthreads();
  {
    const int c = tid & 31, rg = tid >> 5;
    float4 wc[8];
    #pragma unroll
    for (int q = 0; q < 8; q++) wc[q] = *(float4*)&w1[c * 36 + q * 4];
    const float bc = b1[c];
    #pragma unroll
    for (int i = 0; i < 8; i++) {
      int r = rg * 8 + i;
      float a = bc;
      #pragma unroll
      for (int q = 0; q < 8; q++) {
        float4 h4 = *(float4*)&hs[r * 36 + q * 4];
        a += h4.x * wc[q].x + h4.y * wc[q].y + h4.z * wc[q].z + h4.w * wc[q].w;
      }
      fs[r * 36 + c] = fmaxf(a, 0.f);
    }
  }
  __syncthreads();
  for (int idx = tid; idx < 64 * C_OUT; idx += 256) {
    int r = idx / C_OUT, j = idx - r * C_OUT;
    int gr = r0 + r;
    if (gr < N_NODES) {
      float a = b2[j];
      #pragma unroll
      for (int q = 0; q < 8; q++) {
        float4 f4 = *(float4*)&fs[r * 36 + q * 4];
        float4 w4 = *(float4*)&w2[j * 36 + q * 4];
        a += f4.x * w4.x + f4.y * w4.y + f4.z * w4.z + f4.w * w4.w;
      }
      out[(size_t)gr * C_OUT + j] = a;
    }
  }
}

// ---------------------------------------------------------------------------
extern "C" void kernel_launch(void* const* d_in, const int* in_sizes, int n_in,
                              void* d_out, int out_size, void* d_ws, size_t ws_size,
                              hipStream_t stream) {
  const float* x   = (const float*)d_in[0];
  const int* row   = (const int*)d_in[1];
  const int* col   = (const int*)d_in[2];
  const float* W1a = (const float*)d_in[3];
  const float* b1a = (const float*)d_in[4];
  const float* W1b = (const float*)d_in[5];
  const float* b1b = (const float*)d_in[6];
  const float* g1  = (const float*)d_in[7];
  const float* be1 = (const float*)d_in[8];
  const float* W2a = (const float*)d_in[9];
  const float* b2a = (const float*)d_in[10];
  const float* W2b = (const float*)d_in[11];
  const float* b2b = (const float*)d_in[12];
  const float* g2  = (const float*)d_in[13];
  const float* be2 = (const float*)d_in[14];
  const float* Wf1 = (const float*)d_in[15];
  const float* bf1 = (const float*)d_in[16];
  const float* Wf2 = (const float*)d_in[17];
  const float* bf2 = (const float*)d_in[18];
  float* out = (float*)d_out;

  float* ws = (float*)d_ws;
  const size_t NH = (size_t)N_NODES * H_DIM;        // 1.6M
  float* pA    = ws;
  float* zB    = ws + NH;
  float* hC    = ws + 2 * NH;
  float* stats = ws + 3 * NH;                       // 128 floats
  int*   startA = (int*)(ws + 3 * NH + 256);        // N+1 (pad 50016)
  int*   cursor = startA + 50016;                   // N
  int*   deg    = cursor + 50016;                   // N
  int*   ecol   = deg + 50016;                      // E
  const size_t need_bytes = ((3 * NH + 256) + 3 * 50016 + E_EDGES + 512) * 4;
  const bool use_csr = (ws_size >= need_bytes);

  hipMemsetAsync(stats, 0, 128 * sizeof(float), stream);

  const int g64   = (N_NODES + 63) / 64;            // 782
  const int gE    = (E_EDGES + 255) / 256;          // 3125
  const int gHW   = (N_NODES * 32 + 255) / 256;     // 6250
  const int gScat = (E_EDGES * 32 + 255) / 256;     // 100000

  if (use_csr) {
    hipMemsetAsync(deg, 0, 50000 * sizeof(int), stream);
    k_hist <<<gE, 256, 0, stream>>>(row, deg);
    k_scan1<<<1, SCAN_T, 0, stream>>>(deg, startA, cursor);
    k_fill <<<gE, 256, 0, stream>>>(row, col, cursor, ecol);
  }

  // conv1 big GEMM (MFMA split-bf16)
  k_gemm_mfma<<<g64, 256, 0, stream>>>(x, W1a, pA);
  if (use_csr) {
    k_gather<<<gHW, 256, 0, stream>>>(pA, b1a, startA, ecol, zB);
  } else {
    k_zinit<<<g64 * 8, 256, 0, stream>>>(pA, b1a, zB);
    k_scatter<<<gScat, 256, 0, stream>>>(row, col, pA, zB);
  }
  k_mlp_stats<<<g64, 256, 0, stream>>>(zB, W1b, b1b, hC, stats);
  // conv2 (BN1 folded into GEMM)
  k_gemm32_affine<<<g64, 256, 0, stream>>>(hC, stats, g1, be1, W2a, pA);
  if (use_csr) {
    k_gather<<<gHW, 256, 0, stream>>>(pA, b2a, startA, ecol, zB);
  } else {
    k_zinit<<<g64 * 8, 256, 0, stream>>>(pA, b2a, zB);
    k_scatter<<<gScat, 256, 0, stream>>>(row, col, pA, zB);
  }
  k_mlp_stats<<<g64, 256, 0, stream>>>(zB, W2b, b2b, hC, stats + 64);
  // heads (BN2 folded in)
  k_heads<<<g64, 256, 0, stream>>>(hC, stats + 64, g2, be2, Wf1, bf1, Wf2, bf2, out);
}

// Round 6
// 454.915 us; speedup vs baseline: 1.2234x; 1.2234x over previous
//
#include <hip/hip_runtime.h>
#include <hip/hip_bf16.h>

#define N_NODES 50000
#define F_IN    602
#define H_DIM   32
#define C_OUT   41
#define E_EDGES 800000
#define BN_EPS  1e-5f
#define KPAD    608   // F_IN padded to chunk multiple (19*32)

typedef short bf16x8 __attribute__((ext_vector_type(8)));
typedef float f32x4  __attribute__((ext_vector_type(4)));

__device__ inline unsigned short f2bf(float f) {
  unsigned int u = __builtin_bit_cast(unsigned int, f);
  unsigned int r = (u + 0x7FFFu + ((u >> 16) & 1u)) >> 16;
  return (unsigned short)r;
}

// ---------------------------------------------------------------------------
// k_prep: blocks [0,76): split W1a into bf16 hi/lo, transposed to [c][k] pitch
// 608 (zero-padded tail). blocks [76,3201): edge histogram (deg pre-zeroed).
// ---------------------------------------------------------------------------
__global__ __launch_bounds__(256) void k_prep(
    const float* __restrict__ W, unsigned short* __restrict__ wt_hi,
    unsigned short* __restrict__ wt_lo, const int* __restrict__ row,
    int* __restrict__ deg) {
  const int b = blockIdx.x;
  if (b < 76) {
    int idx = b * 256 + threadIdx.x;       // 0..19455 over [k][c]
    int k = idx >> 5, c = idx & 31;
    unsigned short h = 0, l = 0;
    if (k < F_IN) {
      float v = W[(size_t)k * H_DIM + c];
      h = f2bf(v);
      float fh = __builtin_bit_cast(float, (unsigned int)h << 16);
      l = f2bf(v - fh);
    }
    if (k < KPAD) { wt_hi[c * KPAD + k] = h; wt_lo[c * KPAD + k] = l; }
  } else {
    int e = (b - 76) * 256 + threadIdx.x;
    if (e < E_EDGES) atomicAdd(&deg[row[e]], 1);
  }
}

// ---------------------------------------------------------------------------
// K1 v5: p = x @ W1a via split-bf16 MFMA — NO LDS, NO BARRIERS.
// Wave = 16 rows x 32 cols; lane (m,q) loads its A-fragment x[m][8q..8q+7]
// directly from global (fp32), converts to bf16 hi/lo in-register; B-frags
// read from pre-split wt_hi/wt_lo (L2-resident). Register prefetch of next
// chunk's x. 19 chunks of BK=32.
// ---------------------------------------------------------------------------
__global__ __launch_bounds__(256) void k_gemm_mfma2(
    const float* __restrict__ x, const unsigned short* __restrict__ wt_hi,
    const unsigned short* __restrict__ wt_lo, float* __restrict__ p) {
  const int tid = threadIdx.x;
  const int wv = tid >> 6, ln = tid & 63;
  const int m = ln & 15, q = ln >> 4;
  const int r0 = blockIdx.x * 64;
  int rowl = r0 + 16 * wv + m;
  if (rowl > N_NODES - 1) rowl = N_NODES - 1;   // clamp loads; stores masked
  const float* xrow = x + (size_t)rowl * F_IN;
  const unsigned short* pb0h = wt_hi + m * KPAD;
  const unsigned short* pb0l = wt_lo + m * KPAD;
  const unsigned short* pb1h = wt_hi + (m + 16) * KPAD;
  const unsigned short* pb1l = wt_lo + (m + 16) * KPAD;

  f32x4 acc0 = {0.f, 0.f, 0.f, 0.f};
  f32x4 acc1 = {0.f, 0.f, 0.f, 0.f};

  float xf[8];
  auto load_x = [&](int ch) {
    const int k = ch * 32 + 8 * q;
    if (ch == 18 && q == 3) {
      // k=600..607: only 600,601 valid — avoid OOB read past x
      float2 v = *(const float2*)(xrow + 600);
      xf[0] = v.x; xf[1] = v.y;
      xf[2] = 0.f; xf[3] = 0.f; xf[4] = 0.f; xf[5] = 0.f; xf[6] = 0.f; xf[7] = 0.f;
    } else {
      #pragma unroll
      for (int j = 0; j < 4; j++) {      // float2: x rows are 8B-aligned
        float2 v = *(const float2*)(xrow + k + 2 * j);
        xf[2 * j] = v.x; xf[2 * j + 1] = v.y;
      }
    }
  };

  load_x(0);

  for (int ch = 0; ch < 19; ch++) {
    bf16x8 ah, al;
    #pragma unroll
    for (int j = 0; j < 8; j++) {
      unsigned short h = f2bf(xf[j]);
      float fh = __builtin_bit_cast(float, (unsigned int)h << 16);
      unsigned short lo = f2bf(xf[j] - fh);
      ah[j] = (short)h;
      al[j] = (short)lo;
    }
    if (ch < 18) load_x(ch + 1);         // prefetch next chunk
    const int koff = ch * 32 + 8 * q;
    bf16x8 b0h = *(const bf16x8*)(pb0h + koff);
    bf16x8 b0l = *(const bf16x8*)(pb0l + koff);
    bf16x8 b1h = *(const bf16x8*)(pb1h + koff);
    bf16x8 b1l = *(const bf16x8*)(pb1l + koff);
    acc0 = __builtin_amdgcn_mfma_f32_16x16x32_bf16(ah, b0h, acc0, 0, 0, 0);
    acc1 = __builtin_amdgcn_mfma_f32_16x16x32_bf16(ah, b1h, acc1, 0, 0, 0);
    acc0 = __builtin_amdgcn_mfma_f32_16x16x32_bf16(al, b0h, acc0, 0, 0, 0);
    acc1 = __builtin_amdgcn_mfma_f32_16x16x32_bf16(al, b1h, acc1, 0, 0, 0);
    acc0 = __builtin_amdgcn_mfma_f32_16x16x32_bf16(ah, b0l, acc0, 0, 0, 0);
    acc1 = __builtin_amdgcn_mfma_f32_16x16x32_bf16(ah, b1l, acc1, 0, 0, 0);
  }

  // C/D: col = lane&15 (=m), row = (lane>>4)*4 + reg (=4q+reg)
  #pragma unroll
  for (int reg = 0; reg < 4; reg++) {
    int rowg = r0 + 16 * wv + q * 4 + reg;
    if (rowg < N_NODES) {
      p[(size_t)rowg * H_DIM + m]      = acc0[reg];
      p[(size_t)rowg * H_DIM + m + 16] = acc1[reg];
    }
  }
}

// ---------------------------------------------------------------------------
// CSR build: 3-kernel exclusive scan (multi-block — proven) -> fill
// ---------------------------------------------------------------------------
__global__ __launch_bounds__(256) void k_scanA(const int* __restrict__ deg,
                                               int* __restrict__ start,
                                               int* __restrict__ bsum) {
  __shared__ int sc[256];
  int t = threadIdx.x, i = blockIdx.x * 256 + t;
  int v = (i < N_NODES) ? deg[i] : 0;
  sc[t] = v;
  __syncthreads();
  #pragma unroll
  for (int off = 1; off < 256; off <<= 1) {
    int u = (t >= off) ? sc[t - off] : 0;
    __syncthreads();
    sc[t] += u;
    __syncthreads();
  }
  if (i < N_NODES) start[i] = sc[t] - v;
  if (t == 255) bsum[blockIdx.x] = sc[255];
}

__global__ __launch_bounds__(256) void k_scanB(const int* __restrict__ bsum,
                                               int* __restrict__ boff, int nb) {
  __shared__ int sc[256];
  int t = threadIdx.x;
  int v = (t < nb) ? bsum[t] : 0;
  sc[t] = v;
  __syncthreads();
  #pragma unroll
  for (int off = 1; off < 256; off <<= 1) {
    int u = (t >= off) ? sc[t - off] : 0;
    __syncthreads();
    sc[t] += u;
    __syncthreads();
  }
  if (t < nb) boff[t] = sc[t] - v;
}

__global__ __launch_bounds__(256) void k_scanC(int* __restrict__ start,
                                               const int* __restrict__ boff,
                                               int* __restrict__ cursor) {
  int i = blockIdx.x * 256 + threadIdx.x;
  if (i < N_NODES) {
    int s = start[i] + boff[blockIdx.x];
    start[i] = s;
    cursor[i] = s;
  }
  if (i == 0) start[N_NODES] = E_EDGES;
}

__global__ __launch_bounds__(256) void k_fill(const int* __restrict__ row,
                                              const int* __restrict__ col,
                                              int* __restrict__ cursor,
                                              int* __restrict__ ecol) {
  int e = blockIdx.x * 256 + threadIdx.x;
  if (e < E_EDGES) {
    int pos = atomicAdd(&cursor[row[e]], 1);
    ecol[pos] = col[e];
  }
}

// ---------------------------------------------------------------------------
// Gather-aggregate: z[n][c] = p[n][c] + b[c] + sum_{e in CSR[n]} p[ecol[e]][c]
// One half-wave per node (6250 blocks), unroll 8.
// ---------------------------------------------------------------------------
__global__ __launch_bounds__(256) void k_gather(
    const float* __restrict__ p, const float* __restrict__ b,
    const int* __restrict__ start, const int* __restrict__ ecol,
    float* __restrict__ z) {
  int hw = (blockIdx.x * 256 + threadIdx.x) >> 5;
  int c = threadIdx.x & 31;
  if (hw >= N_NODES) return;
  int s = start[hw], e = start[hw + 1];
  float acc = p[(size_t)hw * H_DIM + c] + b[c];
  int i = s;
  for (; i + 7 < e; i += 8) {
    int s0 = ecol[i],     s1 = ecol[i + 1], s2 = ecol[i + 2], s3 = ecol[i + 3];
    int s4 = ecol[i + 4], s5 = ecol[i + 5], s6 = ecol[i + 6], s7 = ecol[i + 7];
    float v0 = p[(size_t)s0 * H_DIM + c];
    float v1 = p[(size_t)s1 * H_DIM + c];
    float v2 = p[(size_t)s2 * H_DIM + c];
    float v3 = p[(size_t)s3 * H_DIM + c];
    float v4 = p[(size_t)s4 * H_DIM + c];
    float v5 = p[(size_t)s5 * H_DIM + c];
    float v6 = p[(size_t)s6 * H_DIM + c];
    float v7 = p[(size_t)s7 * H_DIM + c];
    acc += v0; acc += v1; acc += v2; acc += v3;
    acc += v4; acc += v5; acc += v6; acc += v7;
  }
  for (; i + 3 < e; i += 4) {
    int s0 = ecol[i], s1 = ecol[i + 1], s2 = ecol[i + 2], s3 = ecol[i + 3];
    float v0 = p[(size_t)s0 * H_DIM + c];
    float v1 = p[(size_t)s1 * H_DIM + c];
    float v2 = p[(size_t)s2 * H_DIM + c];
    float v3 = p[(size_t)s3 * H_DIM + c];
    acc += v0; acc += v1; acc += v2; acc += v3;
  }
  for (; i < e; i++) acc += p[(size_t)ecol[i] * H_DIM + c];
  z[(size_t)hw * H_DIM + c] = acc;
}

// ---------------------------------------------------------------------------
// Fallback path (ws too small for CSR)
// ---------------------------------------------------------------------------
__global__ __launch_bounds__(256) void k_zinit(const float* __restrict__ p,
                                               const float* __restrict__ b,
                                               float* __restrict__ z) {
  int i = blockIdx.x * 256 + threadIdx.x;
  if (i < N_NODES * H_DIM) z[i] = p[i] + b[i & 31];
}

__global__ __launch_bounds__(256) void k_scatter(
    const int* __restrict__ row, const int* __restrict__ col,
    const float* __restrict__ p, float* __restrict__ z) {
  long long t = (long long)blockIdx.x * 256 + threadIdx.x;
  int e = (int)(t >> 5);
  int c = (int)(t & 31);
  if (e < E_EDGES) {
    int s = col[e], d = row[e];
    atomicAdd(&z[(size_t)d * H_DIM + c], p[(size_t)s * H_DIM + c]);
  }
}

// ---------------------------------------------------------------------------
// K3: hpre = relu(z) @ W + b  (N x 32 x 32), fused BN partial sums
// ---------------------------------------------------------------------------
__global__ __launch_bounds__(256) void k_mlp_stats(
    const float* __restrict__ z, const float* __restrict__ W,
    const float* __restrict__ b, float* __restrict__ hpre,
    float* __restrict__ stats) {
  __shared__ float as_[64 * 36];
  __shared__ float ws[32 * 36];
  __shared__ float red[512];
  const int tid = threadIdx.x;
  for (int i = tid; i < 1024; i += 256) {
    int k = i >> 5, c = i & 31;
    ws[c * 36 + k] = W[(size_t)k * H_DIM + c];
  }
  const int r0 = blockIdx.x * 64;
  for (int i = tid; i < 2048; i += 256) {
    int r = i >> 5, c = i & 31;
    int gr = r0 + r;
    float v = (gr < N_NODES) ? z[(size_t)gr * H_DIM + c] : 0.f;
    as_[r * 36 + c] = fmaxf(v, 0.f);
  }
  __syncthreads();
  const int c = tid & 31, rg = tid >> 5;
  float4 wc[8];
  #pragma unroll
  for (int q = 0; q < 8; q++) wc[q] = *(float4*)&ws[c * 36 + q * 4];
  const float bc = b[c];
  float lsum = 0.f, lsq = 0.f;
  #pragma unroll
  for (int i = 0; i < 8; i++) {
    int r = rg * 8 + i;
    float a = bc;
    #pragma unroll
    for (int q = 0; q < 8; q++) {
      float4 h4 = *(float4*)&as_[r * 36 + q * 4];
      a += h4.x * wc[q].x + h4.y * wc[q].y + h4.z * wc[q].z + h4.w * wc[q].w;
    }
    int gr = r0 + r;
    if (gr < N_NODES) {
      hpre[(size_t)gr * H_DIM + c] = a;
      lsum += a; lsq += a * a;
    }
  }
  __syncthreads();
  red[tid] = lsum; red[256 + tid] = lsq;
  __syncthreads();
  if (tid < 32) {
    float s = 0.f, q = 0.f;
    #pragma unroll
    for (int g = 0; g < 8; g++) { s += red[g * 32 + tid]; q += red[256 + g * 32 + tid]; }
    atomicAdd(&stats[tid], s);
    atomicAdd(&stats[32 + tid], q);
  }
}

// ---------------------------------------------------------------------------
// K5: p = BN(hpre) @ W  (BN finalize folded in from raw stats)
// ---------------------------------------------------------------------------
__global__ __launch_bounds__(256) void k_gemm32_affine(
    const float* __restrict__ hpre, const float* __restrict__ stats,
    const float* __restrict__ g, const float* __restrict__ be,
    const float* __restrict__ W, float* __restrict__ p) {
  __shared__ float hs[64 * 36];
  __shared__ float ws[32 * 36];
  __shared__ float ssl[64];
  const int tid = threadIdx.x;
  if (tid < 32) {
    float m = stats[tid] * (1.f / N_NODES);
    float v = stats[32 + tid] * (1.f / N_NODES) - m * m;
    float sc = g[tid] * rsqrtf(v + BN_EPS);
    ssl[tid] = sc;
    ssl[32 + tid] = be[tid] - m * sc;
  }
  for (int i = tid; i < 1024; i += 256) {
    int k = i >> 5, c = i & 31;
    ws[c * 36 + k] = W[(size_t)k * H_DIM + c];
  }
  __syncthreads();
  const int r0 = blockIdx.x * 64;
  for (int i = tid; i < 2048; i += 256) {
    int r = i >> 5, c = i & 31;
    int gr = r0 + r;
    float v = (gr < N_NODES) ? hpre[(size_t)gr * H_DIM + c] * ssl[c] + ssl[32 + c] : 0.f;
    hs[r * 36 + c] = v;
  }
  __syncthreads();
  const int c = tid & 31, rg = tid >> 5;
  float4 wc[8];
  #pragma unroll
  for (int q = 0; q < 8; q++) wc[q] = *(float4*)&ws[c * 36 + q * 4];
  #pragma unroll
  for (int i = 0; i < 8; i++) {
    int r = rg * 8 + i;
    float a = 0.f;
    #pragma unroll
    for (int q = 0; q < 8; q++) {
      float4 h4 = *(float4*)&hs[r * 36 + q * 4];
      a += h4.x * wc[q].x + h4.y * wc[q].y + h4.z * wc[q].z + h4.w * wc[q].w;
    }
    int gr = r0 + r;
    if (gr < N_NODES) p[(size_t)gr * H_DIM + c] = a;
  }
}

// ---------------------------------------------------------------------------
// K6: heads: out = relu(BN(hpre)@Wf1 + bf1) @ Wf2 + bf2 (BN folded in)
// ---------------------------------------------------------------------------
__global__ __launch_bounds__(256) void k_heads(
    const float* __restrict__ hpre, const float* __restrict__ stats,
    const float* __restrict__ g, const float* __restrict__ be,
    const float* __restrict__ W1, const float* __restrict__ b1,
    const float* __restrict__ W2, const float* __restrict__ b2,
    float* __restrict__ out) {
  __shared__ float hs[64 * 36];
  __shared__ float fs[64 * 36];
  __shared__ float w1[32 * 36];
  __shared__ float w2[41 * 36];
  __shared__ float ssl[64];
  const int tid = threadIdx.x;
  if (tid < 32) {
    float m = stats[tid] * (1.f / N_NODES);
    float v = stats[32 + tid] * (1.f / N_NODES) - m * m;
    float sc = g[tid] * rsqrtf(v + BN_EPS);
    ssl[tid] = sc;
    ssl[32 + tid] = be[tid] - m * sc;
  }
  for (int i = tid; i < 1024; i += 256) {
    int k = i >> 5, c = i & 31;
    w1[c * 36 + k] = W1[(size_t)k * H_DIM + c];
  }
  for (int i = tid; i < 41 * 32; i += 256) {
    int j = i >> 5, k = i & 31;
    w2[j * 36 + k] = W2[(size_t)k * C_OUT + j];
  }
  __syncthreads();
  const int r0 = blockIdx.x * 64;
  for (int i = tid; i < 2048; i += 256) {
    int r = i >> 5, c = i & 31;
    int gr = r0 + r;
    hs[r * 36 + c] = (gr < N_NODES) ? hpre[(size_t)gr * H_DIM + c] * ssl[c] + ssl[32 + c] : 0.f;
  }
  __syncthreads();
  {
    const int c = tid & 31, rg = tid >> 5;
    float4 wc[8];
    #pragma unroll
    for (int q = 0; q < 8; q++) wc[q] = *(float4*)&w1[c * 36 + q * 4];
    const float bc = b1[c];
    #pragma unroll
    for (int i = 0; i < 8; i++) {
      int r = rg * 8 + i;
      float a = bc;
      #pragma unroll
      for (int q = 0; q < 8; q++) {
        float4 h4 = *(float4*)&hs[r * 36 + q * 4];
        a += h4.x * wc[q].x + h4.y * wc[q].y + h4.z * wc[q].z + h4.w * wc[q].w;
      }
      fs[r * 36 + c] = fmaxf(a, 0.f);
    }
  }
  __syncthreads();
  for (int idx = tid; idx < 64 * C_OUT; idx += 256) {
    int r = idx / C_OUT, j = idx - r * C_OUT;
    int gr = r0 + r;
    if (gr < N_NODES) {
      float a = b2[j];
      #pragma unroll
      for (int q = 0; q < 8; q++) {
        float4 f4 = *(float4*)&fs[r * 36 + q * 4];
        float4 w4 = *(float4*)&w2[j * 36 + q * 4];
        a += f4.x * w4.x + f4.y * w4.y + f4.z * w4.z + f4.w * w4.w;
      }
      out[(size_t)gr * C_OUT + j] = a;
    }
  }
}

// ---------------------------------------------------------------------------
extern "C" void kernel_launch(void* const* d_in, const int* in_sizes, int n_in,
                              void* d_out, int out_size, void* d_ws, size_t ws_size,
                              hipStream_t stream) {
  const float* x   = (const float*)d_in[0];
  const int* row   = (const int*)d_in[1];
  const int* col   = (const int*)d_in[2];
  const float* W1a = (const float*)d_in[3];
  const float* b1a = (const float*)d_in[4];
  const float* W1b = (const float*)d_in[5];
  const float* b1b = (const float*)d_in[6];
  const float* g1  = (const float*)d_in[7];
  const float* be1 = (const float*)d_in[8];
  const float* W2a = (const float*)d_in[9];
  const float* b2a = (const float*)d_in[10];
  const float* W2b = (const float*)d_in[11];
  const float* b2b = (const float*)d_in[12];
  const float* g2  = (const float*)d_in[13];
  const float* be2 = (const float*)d_in[14];
  const float* Wf1 = (const float*)d_in[15];
  const float* bf1 = (const float*)d_in[16];
  const float* Wf2 = (const float*)d_in[17];
  const float* bf2 = (const float*)d_in[18];
  float* out = (float*)d_out;

  float* ws = (float*)d_ws;
  const size_t NH = (size_t)N_NODES * H_DIM;        // 1.6M
  float* pA    = ws;
  float* zB    = ws + NH;
  float* hC    = ws + 2 * NH;
  float* stats = ws + 3 * NH;                       // 128 floats
  int*   deg    = (int*)(stats + 128);              // 50016 (contig w/ stats)
  int*   startA = deg + 50016;                      // N+1
  int*   cursor = startA + 50016;                   // N
  int*   ecol   = cursor + 50016;                   // E
  int*   bsum   = ecol + E_EDGES;                   // 256
  int*   boff   = bsum + 256;                       // 256
  const size_t csr_need = ((3 * NH + 128) + 3 * 50016 + E_EDGES + 512) * 4
                          + 2 * KPAD * 32 * 2;
  const bool use_csr = (ws_size >= csr_need);
  unsigned short* wt_hi = use_csr ? (unsigned short*)(boff + 256)
                                  : (unsigned short*)(stats + 128);
  unsigned short* wt_lo = wt_hi + KPAD * 32;

  const int g64   = (N_NODES + 63) / 64;            // 782
  const int gE    = (E_EDGES + 255) / 256;          // 3125
  const int gN    = (N_NODES + 255) / 256;          // 196
  const int gHW   = (N_NODES * 32 + 255) / 256;     // 6250
  const int gScat = (E_EDGES * 32 + 255) / 256;     // 100000

  if (use_csr) {
    // one memset covers stats (128 f) + deg (50016 i), contiguous
    hipMemsetAsync(stats, 0, (128 + 50016) * sizeof(int), stream);
    k_prep <<<76 + gE, 256, 0, stream>>>(W1a, wt_hi, wt_lo, row, deg);
    k_scanA<<<gN, 256, 0, stream>>>(deg, startA, bsum);
    k_scanB<<<1, 256, 0, stream>>>(bsum, boff, gN);
    k_scanC<<<gN, 256, 0, stream>>>(startA, boff, cursor);
    k_fill <<<gE, 256, 0, stream>>>(row, col, cursor, ecol);
    k_gemm_mfma2<<<g64, 256, 0, stream>>>(x, wt_hi, wt_lo, pA);
    k_gather<<<gHW, 256, 0, stream>>>(pA, b1a, startA, ecol, zB);
    k_mlp_stats<<<g64, 256, 0, stream>>>(zB, W1b, b1b, hC, stats);
    k_gemm32_affine<<<g64, 256, 0, stream>>>(hC, stats, g1, be1, W2a, pA);
    k_gather<<<gHW, 256, 0, stream>>>(pA, b2a, startA, ecol, zB);
    k_mlp_stats<<<g64, 256, 0, stream>>>(zB, W2b, b2b, hC, stats + 64);
    k_heads<<<g64, 256, 0, stream>>>(hC, stats + 64, g2, be2, Wf1, bf1, Wf2, bf2, out);
  } else {
    hipMemsetAsync(stats, 0, 128 * sizeof(float), stream);
    k_prep <<<76, 256, 0, stream>>>(W1a, wt_hi, wt_lo, row, (int*)nullptr);
    k_gemm_mfma2<<<g64, 256, 0, stream>>>(x, wt_hi, wt_lo, pA);
    k_zinit<<<g64 * 8, 256, 0, stream>>>(pA, b1a, zB);
    k_scatter<<<gScat, 256, 0, stream>>>(row, col, pA, zB);
    k_mlp_stats<<<g64, 256, 0, stream>>>(zB, W1b, b1b, hC, stats);
    k_gemm32_affine<<<g64, 256, 0, stream>>>(hC, stats, g1, be1, W2a, pA);
    k_zinit<<<g64 * 8, 256, 0, stream>>>(pA, b2a, zB);
    k_scatter<<<gScat, 256, 0, stream>>>(row, col, pA, zB);
    k_mlp_stats<<<g64, 256, 0, stream>>>(zB, W2b, b2b, hC, stats + 64);
    k_heads<<<g64, 256, 0, stream>>>(hC, stats + 64, g2, be2, Wf1, bf1, Wf2, bf2, out);
  }
}